// Round 1
// baseline (504.384 us; speedup 1.0000x reference)
//
#include <hip/hip_runtime.h>

// RefWignerRotation: out[n, off + m*d + i, c] = sum_j D^l_n[i,j] * x[n, off + m*d + j, c]
// IRREPS: (l=0,mul=128) rows 0..127 | (l=1,64) rows 128..319 | (l=2,32) rows 320..479 | (l=3,16) rows 480..591
// DIM=592, C=16, N=8192. Memory-bound: 620 MB total traffic, roofline ~98us.
//
// D^l = A(alpha) * B(beta) * A(gamma) where (derived analytically from the reference's
// generator construction; indices 0..2l, real SH basis):
//   A(theta): pair (l-mu, l+mu) rotates by mu*theta: [[c,s],[-s,c]]; index l fixed.
//   B(beta): block-diagonal over sin-chain (idx<l) and cos-chain (idx>=l); every entry is
//            k0 + c1*cosb + s1*sinb + c2*cos2b + s2*sin2b + c3*cos3b + s3*sin3b  (7-term table).

#define NUM_SAMPLES 8192
#define SAMPLE_F 9472      // 592*16 floats per sample
#define SAMPLE_F4 2368     // float4 per sample

// 83 D entries: l=1 -> t=0..8 (i*3+j), l=2 -> t=9..33 (9+i*5+j), l=3 -> t=34..82 (34+i*7+j)
// 7 coeffs each: (k0, cosb, sinb, cos2b, sin2b, cos3b, sin3b)
__device__ __constant__ float CB[83 * 7] = {
    // ---- l=1 (d=3) ----
    1,0,0,0,0,0,0,          // (0,0)
    0,0,0,0,0,0,0,          // (0,1)
    0,0,0,0,0,0,0,          // (0,2)
    0,0,0,0,0,0,0,          // (1,0)
    0,1,0,0,0,0,0,          // (1,1) cosb
    0,0,-1,0,0,0,0,         // (1,2) -sinb
    0,0,0,0,0,0,0,          // (2,0)
    0,0,1,0,0,0,0,          // (2,1) sinb
    0,1,0,0,0,0,0,          // (2,2) cosb
    // ---- l=2 (d=5) ----
    0,1,0,0,0,0,0,          // (0,0) cosb
    0,0,1,0,0,0,0,          // (0,1) sinb
    0,0,0,0,0,0,0,          // (0,2)
    0,0,0,0,0,0,0,          // (0,3)
    0,0,0,0,0,0,0,          // (0,4)
    0,0,-1,0,0,0,0,         // (1,0) -sinb
    0,1,0,0,0,0,0,          // (1,1) cosb
    0,0,0,0,0,0,0,          // (1,2)
    0,0,0,0,0,0,0,          // (1,3)
    0,0,0,0,0,0,0,          // (1,4)
    0,0,0,0,0,0,0,          // (2,0)
    0,0,0,0,0,0,0,          // (2,1)
    0.25f,0,0,0.75f,0,0,0,                         // (2,2)
    0,0,0,0,-0.8660254037844387f,0,0,              // (2,3)
    0.4330127018922193f,0,0,-0.4330127018922193f,0,0,0,  // (2,4)
    0,0,0,0,0,0,0,          // (3,0)
    0,0,0,0,0,0,0,          // (3,1)
    0,0,0,0,0.8660254037844387f,0,0,               // (3,2)
    0,0,0,1,0,0,0,                                 // (3,3) cos2b
    0,0,0,0,-0.5f,0,0,                             // (3,4)
    0,0,0,0,0,0,0,          // (4,0)
    0,0,0,0,0,0,0,          // (4,1)
    0.4330127018922193f,0,0,-0.4330127018922193f,0,0,0,  // (4,2)
    0,0,0,0,0.5f,0,0,                              // (4,3)
    0.75f,0,0,0.25f,0,0,0,                         // (4,4)
    // ---- l=3 (d=7) ----
    0.625f,0,0,0.375f,0,0,0,                       // (0,0)
    0,0,0,0,0.6123724356957945f,0,0,               // (0,1)
    0.4841229182759271f,0,0,-0.4841229182759271f,0,0,0,  // (0,2)
    0,0,0,0,0,0,0, 0,0,0,0,0,0,0, 0,0,0,0,0,0,0, 0,0,0,0,0,0,0, // (0,3..6)
    0,0,0,0,-0.6123724356957945f,0,0,              // (1,0)
    0,0,0,1,0,0,0,                                 // (1,1) cos2b
    0,0,0,0,0.7905694150420949f,0,0,               // (1,2)
    0,0,0,0,0,0,0, 0,0,0,0,0,0,0, 0,0,0,0,0,0,0, 0,0,0,0,0,0,0, // (1,3..6)
    0.4841229182759271f,0,0,-0.4841229182759271f,0,0,0,  // (2,0)
    0,0,0,0,-0.7905694150420949f,0,0,              // (2,1)
    0.375f,0,0,0.625f,0,0,0,                       // (2,2)
    0,0,0,0,0,0,0, 0,0,0,0,0,0,0, 0,0,0,0,0,0,0, 0,0,0,0,0,0,0, // (2,3..6)
    0,0,0,0,0,0,0, 0,0,0,0,0,0,0, 0,0,0,0,0,0,0,  // (3,0..2)
    0,0.375f,0,0,0,0.625f,0,                       // (3,3)
    0,0,-0.1530931089239487f,0,0,0,-0.7654655446197435f, // (3,4)
    0,0.4841229182759271f,0,0,0,-0.4841229182759271f,0,  // (3,5)
    0,0,-0.5929270612815711f,0,0,0,0.1976423537605237f,  // (3,6)
    0,0,0,0,0,0,0, 0,0,0,0,0,0,0, 0,0,0,0,0,0,0,  // (4,0..2)
    0,0,0.1530931089239487f,0,0,0,0.7654655446197435f,   // (4,3)
    0,0.0625f,0,0,0,0.9375f,0,                     // (4,4)
    0,0,0.1976423537605237f,0,0,0,-0.5929270612815711f,  // (4,5)
    0,0.2420614591379636f,0,0,0,-0.2420614591379636f,0,  // (4,6)
    0,0,0,0,0,0,0, 0,0,0,0,0,0,0, 0,0,0,0,0,0,0,  // (5,0..2)
    0,0.4841229182759271f,0,0,0,-0.4841229182759271f,0,  // (5,3)
    0,0,-0.1976423537605237f,0,0,0,0.5929270612815711f,  // (5,4)
    0,0.625f,0,0,0,0.375f,0,                       // (5,5)
    0,0,-0.7654655446197435f,0,0,0,-0.1530931089239487f, // (5,6)
    0,0,0,0,0,0,0, 0,0,0,0,0,0,0, 0,0,0,0,0,0,0,  // (6,0..2)
    0,0,0.5929270612815711f,0,0,0,-0.1976423537605237f,  // (6,3)
    0,0.2420614591379636f,0,0,0,-0.2420614591379636f,0,  // (6,4)
    0,0,0.7654655446197435f,0,0,0,0.1530931089239487f,   // (6,5)
    0,0.9375f,0,0,0,0.0625f,0,                     // (6,6)
};

__device__ inline float4 f4_fma(float s, float4 x, float4 a) {
    a.x += s * x.x; a.y += s * x.y; a.z += s * x.z; a.w += s * x.w; return a;
}
__device__ inline float4 f4_mul(float s, float4 x) {
    float4 r; r.x = s * x.x; r.y = s * x.y; r.z = s * x.z; r.w = s * x.w; return r;
}

__global__ __launch_bounds__(256) void wigner_kernel(
    const float* __restrict__ x, const float* __restrict__ alpha,
    const float* __restrict__ beta, const float* __restrict__ gamma,
    float* __restrict__ out)
{
    __shared__ float sD[84];
    const int n = blockIdx.x;
    const int t = threadIdx.x;

    // ---------------- Phase 1: D entries -> LDS (threads 0..82) ----------------
    if (t < 83) {
        int l, i, j, base;
        if (t < 9)       { l = 1; base = 0;  int e = t;      i = e / 3; j = e - i * 3; }
        else if (t < 34) { l = 2; base = 9;  int e = t - 9;  i = e / 5; j = e - i * 5; }
        else             { l = 3; base = 34; int e = t - 34; i = e / 7; j = e - i * 7; }
        const int d = 2 * l + 1;

        const float a = alpha[n], b = beta[n], g = gamma[n];
        float cb1, sb1;
        __sincosf(b, &sb1, &cb1);
        const float cb2 = cb1 * cb1 - sb1 * sb1, sb2 = 2.f * sb1 * cb1;
        const float cb3 = cb2 * cb1 - sb2 * sb1, sb3 = sb2 * cb1 + cb2 * sb1;

        auto Bent = [&](int p, int q) -> float {
            const float* cc = &CB[(base + p * d + q) * 7];
            return cc[0] + cc[1] * cb1 + cc[2] * sb1 + cc[3] * cb2
                 + cc[4] * sb2 + cc[5] * cb3 + cc[6] * sb3;
        };

        const int ip = 2 * l - i, jp = 2 * l - j;
        // left (alpha) coefficients: row_i(A(alpha)*B) = u*B[i,:] + v*B[ip,:]
        float u, v;
        {
            const int mu = (i < l) ? (l - i) : (i - l);
            float sa, ca;
            __sincosf((float)mu * a, &sa, &ca);
            if (i < l)      { u = ca;  v = sa; }
            else if (i == l){ u = 1.f; v = 0.f; }
            else            { u = ca;  v = -sa; }
        }
        // right (gamma) coefficients: D[i,j] = p_*M[i,j] + q_*M[i,jp]
        float p_, q_;
        {
            const int mu = (j < l) ? (l - j) : (j - l);
            float sg, cg;
            __sincosf((float)mu * g, &sg, &cg);
            if (j < l)      { p_ = cg;  q_ = -sg; }
            else if (j == l){ p_ = 1.f; q_ = 0.f; }
            else            { p_ = cg;  q_ = sg; }
        }
        const float Mij  = u * Bent(i, j)  + v * Bent(ip, j);
        const float Mijp = u * Bent(i, jp) + v * Bent(ip, jp);
        sD[t] = p_ * Mij + q_ * Mijp;
    }
    __syncthreads();

    // ---------------- Phase 2: streaming apply (float4 over channels) ----------------
    const float4* __restrict__ xs4 = (const float4*)(x + (size_t)n * SAMPLE_F);
    float4* __restrict__ os4 = (float4*)(out + (size_t)n * SAMPLE_F);

    // l=0: rows 0..127 pure copy (512 float4)
    os4[t] = xs4[t];
    os4[t + 256] = xs4[t + 256];

    // l=1: 64 m-blocks x 4 float4-channels = 256 units (all threads)
    {
        const int m = t >> 2, c4 = t & 3;
        const int r4 = (128 + 3 * m) * 4 + c4;
        const float4 x0 = xs4[r4], x1 = xs4[r4 + 4], x2 = xs4[r4 + 8];
        float4 y;
        y = f4_mul(sD[0], x0); y = f4_fma(sD[1], x1, y); y = f4_fma(sD[2], x2, y);
        os4[r4] = y;
        y = f4_mul(sD[3], x0); y = f4_fma(sD[4], x1, y); y = f4_fma(sD[5], x2, y);
        os4[r4 + 4] = y;
        y = f4_mul(sD[6], x0); y = f4_fma(sD[7], x1, y); y = f4_fma(sD[8], x2, y);
        os4[r4 + 8] = y;
    }

    // l=2: 32 m-blocks x 4 = 128 units (threads 0..127)
    if (t < 128) {
        const int m = t >> 2, c4 = t & 3;
        const int r4 = (320 + 5 * m) * 4 + c4;
        float4 xv[5];
        #pragma unroll
        for (int j = 0; j < 5; ++j) xv[j] = xs4[r4 + 4 * j];
        #pragma unroll
        for (int i = 0; i < 5; ++i) {
            float4 y = f4_mul(sD[9 + i * 5], xv[0]);
            #pragma unroll
            for (int j = 1; j < 5; ++j) y = f4_fma(sD[9 + i * 5 + j], xv[j], y);
            os4[r4 + 4 * i] = y;
        }
    }

    // l=3: 16 m-blocks x 4 = 64 units (threads 128..191)
    if (t >= 128 && t < 192) {
        const int e = t - 128;
        const int m = e >> 2, c4 = e & 3;
        const int r4 = (480 + 7 * m) * 4 + c4;
        float4 xv[7];
        #pragma unroll
        for (int j = 0; j < 7; ++j) xv[j] = xs4[r4 + 4 * j];
        #pragma unroll
        for (int i = 0; i < 7; ++i) {
            float4 y = f4_mul(sD[34 + i * 7], xv[0]);
            #pragma unroll
            for (int j = 1; j < 7; ++j) y = f4_fma(sD[34 + i * 7 + j], xv[j], y);
            os4[r4 + 4 * i] = y;
        }
    }
}

extern "C" void kernel_launch(void* const* d_in, const int* in_sizes, int n_in,
                              void* d_out, int out_size, void* d_ws, size_t ws_size,
                              hipStream_t stream) {
    const float* x     = (const float*)d_in[0];
    const float* alpha = (const float*)d_in[1];
    const float* beta  = (const float*)d_in[2];
    const float* gamma = (const float*)d_in[3];
    float* out = (float*)d_out;
    const int n = in_sizes[1];  // 8192 samples
    wigner_kernel<<<dim3(n), dim3(256), 0, stream>>>(x, alpha, beta, gamma, out);
}